// Round 1
// baseline (1010.626 us; speedup 1.0000x reference)
//
#include <hip/hip_runtime.h>
#include <float.h>

#define NROWS 8192
#define DIM 128
#define MARGIN 0.5f

// ---------------------------------------------------------------------------
// Kernel 1: xn[i] = dot(x[i], x[i]); class histogram cc[c].
// One wave per row; lane handles 2 floats; butterfly reduce.
// ---------------------------------------------------------------------------
__global__ __launch_bounds__(256) void xn_cc_kernel(const float* __restrict__ x,
                                                    const int* __restrict__ tgt,
                                                    float* __restrict__ xn,
                                                    int* __restrict__ cc) {
    const int wid  = threadIdx.x >> 6;
    const int lane = threadIdx.x & 63;
    const int row  = blockIdx.x * 4 + wid;
    const float2 v = *(const float2*)(x + (size_t)row * DIM + lane * 2);
    float s = v.x * v.x + v.y * v.y;
    #pragma unroll
    for (int off = 32; off > 0; off >>= 1) s += __shfl_xor(s, off, 64);
    if (lane == 0) {
        xn[row] = s;
        atomicAdd(&cc[tgt[row]], 1);
    }
}

// ---------------------------------------------------------------------------
// Kernel 2: fused distance GEMM + per-row mining.
// Block = 256 threads (tx=16 j-dir, ty=16 i-dir), owns 32 rows (i0..i0+31),
// scans all 8192 columns in 64-wide tiles. Micro-tile 2(i) x 4(j) per thread.
// d[i][j] = clip(xn[i] + xn[j] - 2*dot(x_i,x_j), 0)  (diag residual ~1e-3,
// irrelevant for argmax/argmin since real distances are O(100)).
// g_pos = argmax over same-class (first occurrence), g_neg = argmin over diff.
// ---------------------------------------------------------------------------
__global__ __launch_bounds__(256) void mine_kernel(const float* __restrict__ x,
                                                   const int* __restrict__ tgt,
                                                   const float* __restrict__ xn,
                                                   int* __restrict__ g_pos,
                                                   int* __restrict__ g_neg) {
    // A transposed [k][i], pad 36: float2 reads At[k][2ty] conflict-free.
    __shared__ float At[DIM][36];
    // B row-major [j][k], pad 65: scalar reads Bs[4tx+jj][k] are 2-way (free).
    __shared__ float Bs[64][65];

    const int tid = threadIdx.x;
    const int tx = tid & 15, ty = tid >> 4;
    const int ty2 = ty * 2, tx4 = tx * 4;
    const int i0 = blockIdx.x * 32;
    const float4* Xv = (const float4*)x;

    // stage A transposed (once per block)
    for (int f = tid; f < 32 * 32; f += 256) {
        int row = f >> 5, kv = f & 31;
        float4 v = Xv[(size_t)(i0 + row) * 32 + kv];
        int kb = kv * 4;
        At[kb][row] = v.x; At[kb + 1][row] = v.y;
        At[kb + 2][row] = v.z; At[kb + 3][row] = v.w;
    }

    const int ti0 = tgt[i0 + ty2], ti1 = tgt[i0 + ty2 + 1];
    const float xni0 = xn[i0 + ty2], xni1 = xn[i0 + ty2 + 1];

    float mx0 = -FLT_MAX, mx1 = -FLT_MAX, mn0 = FLT_MAX, mn1 = FLT_MAX;
    int mxj0 = 0, mxj1 = 0, mnj0 = 0, mnj1 = 0;

    for (int jt = 0; jt < NROWS / 64; ++jt) {
        const int j0 = jt * 64;
        __syncthreads();
        // stage B tile row-major
        for (int f = tid; f < 64 * 32; f += 256) {
            int row = f >> 5, kv = f & 31;
            float4 v = Xv[(size_t)(j0 + row) * 32 + kv];
            int kb = kv * 4;
            Bs[row][kb] = v.x; Bs[row][kb + 1] = v.y;
            Bs[row][kb + 2] = v.z; Bs[row][kb + 3] = v.w;
        }
        __syncthreads();

        float acc[2][4] = {{0.f, 0.f, 0.f, 0.f}, {0.f, 0.f, 0.f, 0.f}};
        #pragma unroll 4
        for (int k = 0; k < DIM; ++k) {
            float a0 = At[k][ty2], a1 = At[k][ty2 + 1];
            float b0 = Bs[tx4][k], b1 = Bs[tx4 + 1][k];
            float b2 = Bs[tx4 + 2][k], b3 = Bs[tx4 + 3][k];
            acc[0][0] = fmaf(a0, b0, acc[0][0]);
            acc[0][1] = fmaf(a0, b1, acc[0][1]);
            acc[0][2] = fmaf(a0, b2, acc[0][2]);
            acc[0][3] = fmaf(a0, b3, acc[0][3]);
            acc[1][0] = fmaf(a1, b0, acc[1][0]);
            acc[1][1] = fmaf(a1, b1, acc[1][1]);
            acc[1][2] = fmaf(a1, b2, acc[1][2]);
            acc[1][3] = fmaf(a1, b3, acc[1][3]);
        }

        // mining update (j strictly ascending per thread -> strict compare
        // keeps first occurrence among this thread's candidates)
        #pragma unroll
        for (int jj = 0; jj < 4; ++jj) {
            int j = j0 + tx4 + jj;
            float xnj = xn[j];
            int tj = tgt[j];
            float d0 = fmaxf(xni0 + xnj - 2.0f * acc[0][jj], 0.0f);
            float d1 = fmaxf(xni1 + xnj - 2.0f * acc[1][jj], 0.0f);
            if (tj == ti0) { if (d0 > mx0) { mx0 = d0; mxj0 = j; } }
            else           { if (d0 < mn0) { mn0 = d0; mnj0 = j; } }
            if (tj == ti1) { if (d1 > mx1) { mx1 = d1; mxj1 = j; } }
            else           { if (d1 < mn1) { mn1 = d1; mnj1 = j; } }
        }
    }

    // cross-thread (over tx) reduction via LDS scratch (reuse At)
    __syncthreads();
    float4* scr = (float4*)&At[0][0];   // 32 rows x 16 entries = 8 KB
    scr[ty2 * 16 + tx]       = make_float4(mx0, __int_as_float(mxj0), mn0, __int_as_float(mnj0));
    scr[(ty2 + 1) * 16 + tx] = make_float4(mx1, __int_as_float(mxj1), mn1, __int_as_float(mnj1));
    __syncthreads();
    if (tid < 32) {
        float bx = -FLT_MAX, bn = FLT_MAX;
        int bxj = 0, bnj = 0;
        #pragma unroll 4
        for (int e = 0; e < 16; ++e) {
            float4 v = scr[tid * 16 + e];
            int j1 = __float_as_int(v.y);
            if (v.x > bx || (v.x == bx && j1 < bxj)) { bx = v.x; bxj = j1; }
            int j2 = __float_as_int(v.w);
            if (v.z < bn || (v.z == bn && j2 < bnj)) { bn = v.z; bnj = j2; }
        }
        g_pos[i0 + tid] = bxj;
        g_neg[i0 + tid] = bnj;
    }
}

// ---------------------------------------------------------------------------
// Kernel 3: fused rank (subset-position "bug") + loss terms.
// One wave per row: ballot-popcount of same/diff class below g_pos/g_neg
// gives p_pos/p_neg; then gather x[p_pos], x[p_neg], compute ap/an/npd/l1,
// block-reduce into 7 global fp32 accumulators.
// ---------------------------------------------------------------------------
__global__ __launch_bounds__(256) void rank_loss_kernel(const float* __restrict__ x,
                                                        const int* __restrict__ tgt,
                                                        const int* __restrict__ g_pos,
                                                        const int* __restrict__ g_neg,
                                                        const int* __restrict__ cc,
                                                        float* __restrict__ gacc) {
    __shared__ float s_acc[7];
    const int tid = threadIdx.x;
    if (tid < 7) s_acc[tid] = 0.0f;
    __syncthreads();

    const int wid = tid >> 6, lane = tid & 63;
    const int r = blockIdx.x * 4 + wid;
    const int gp = g_pos[r], gn = g_neg[r], ti = tgt[r];
    const int lim = max(gp, gn);

    int cp = 0, cn = 0;
    for (int j0 = 0; j0 < lim; j0 += 64) {
        int j = j0 + lane;
        int tj = (j < lim) ? tgt[j] : ti;               // inactive lanes neutral
        cp += __popcll(__ballot(j < gp && tj == ti));   // same-class below g_pos
        cn += __popcll(__ballot(j < gn && tj != ti));   // diff-class below g_neg
    }
    const int pp = cp, pn = cn;   // uniform across wave

    const float2 a = *(const float2*)(x + (size_t)r * DIM + lane * 2);
    const float2 p = *(const float2*)(x + (size_t)pp * DIM + lane * 2);
    const float2 q = *(const float2*)(x + (size_t)pn * DIM + lane * 2);
    float dap = (a.x - p.x) * (a.x - p.x) + (a.y - p.y) * (a.y - p.y);
    float dan = (a.x - q.x) * (a.x - q.x) + (a.y - q.y) * (a.y - q.y);
    float dpn = (p.x - q.x) * (p.x - q.x) + (p.y - q.y) * (p.y - q.y);
    float l1  = fabsf(a.x) + fabsf(a.y) + fabsf(p.x) + fabsf(p.y)
              + fabsf(q.x) + fabsf(q.y);
    #pragma unroll
    for (int off = 32; off > 0; off >>= 1) {
        dap += __shfl_xor(dap, off, 64);
        dan += __shfl_xor(dan, off, 64);
        dpn += __shfl_xor(dpn, off, 64);
        l1  += __shfl_xor(l1,  off, 64);
    }
    if (lane == 0) {
        int c = cc[ti];
        float vf = (c > 1 && (NROWS - c) >= 1) ? 1.0f : 0.0f;
        float tl = fmaxf(dap - dan + MARGIN, 0.0f) * vf;
        atomicAdd(&s_acc[0], tl);
        atomicAdd(&s_acc[1], (tl > 0.0f) ? 1.0f : 0.0f);
        atomicAdd(&s_acc[2], vf);
        atomicAdd(&s_acc[3], l1 * vf);
        atomicAdd(&s_acc[4], (dap - dan - dpn) * vf);
        atomicAdd(&s_acc[5], dap * vf);
        atomicAdd(&s_acc[6], dan * vf);
    }
    __syncthreads();
    if (tid < 7) atomicAdd(&gacc[tid], s_acc[tid]);
}

// ---------------------------------------------------------------------------
// Kernel 4: finalize 6 outputs.
// ---------------------------------------------------------------------------
__global__ void final_kernel(const float* __restrict__ g, float* __restrict__ out) {
    if (threadIdx.x == 0) {
        float tl = g[0], nz = g[1], vc = g[2], l1 = g[3];
        float pw = g[4], apS = g[5], anS = g[6];
        out[0] = (nz == 0.0f) ? (tl / vc) : (tl / fmaxf(nz, 1.0f));
        out[1] = (l1 / vc) * (1.0f / 3.0f);
        out[2] = fmaxf(pw / vc, 0.0f);
        out[3] = vc;
        out[4] = apS / vc;
        out[5] = anS / vc;
    }
}

extern "C" void kernel_launch(void* const* d_in, const int* in_sizes, int n_in,
                              void* d_out, int out_size, void* d_ws, size_t ws_size,
                              hipStream_t stream) {
    const float* x   = (const float*)d_in[0];
    const int*   tgt = (const int*)d_in[1];
    float* out = (float*)d_out;
    float* ws  = (float*)d_ws;

    float* xn    = ws;                          // [0, N)
    int*   g_pos = (int*)(ws + NROWS);          // [N, 2N)
    int*   g_neg = (int*)(ws + 2 * NROWS);      // [2N, 3N)
    float* gacc  = ws + 3 * NROWS;              // 7 floats
    int*   cc    = (int*)(ws + 3 * NROWS + 8);  // 64 ints

    // zero accumulators + class histogram (ws is poisoned 0xAA each call)
    hipMemsetAsync(gacc, 0, (8 + 64) * sizeof(float), stream);

    xn_cc_kernel<<<NROWS / 4, 256, 0, stream>>>(x, tgt, xn, cc);
    mine_kernel<<<NROWS / 32, 256, 0, stream>>>(x, tgt, xn, g_pos, g_neg);
    rank_loss_kernel<<<NROWS / 4, 256, 0, stream>>>(x, tgt, g_pos, g_neg, cc, gacc);
    final_kernel<<<1, 64, 0, stream>>>(gacc, out);
}

// Round 2
// 293.914 us; speedup vs baseline: 3.4385x; 3.4385x over previous
//
#include <hip/hip_runtime.h>
#include <float.h>

#define NROWS 8192
#define DIM 128
#define MARGIN 0.5f

typedef __attribute__((ext_vector_type(8))) short short8;   // 8 bf16 = 4 VGPRs
typedef __attribute__((ext_vector_type(4))) float floatx4;  // MFMA C/D

// ---------------------------------------------------------------------------
// Kernel 1: xn[i] = dot(x[i], x[i]); class histogram cc[c].
// ---------------------------------------------------------------------------
__global__ __launch_bounds__(256) void xn_cc_kernel(const float* __restrict__ x,
                                                    const int* __restrict__ tgt,
                                                    float* __restrict__ xn,
                                                    int* __restrict__ cc) {
    const int wid  = threadIdx.x >> 6;
    const int lane = threadIdx.x & 63;
    const int row  = blockIdx.x * 4 + wid;
    const float2 v = *(const float2*)(x + (size_t)row * DIM + lane * 2);
    float s = v.x * v.x + v.y * v.y;
    #pragma unroll
    for (int off = 32; off > 0; off >>= 1) s += __shfl_xor(s, off, 64);
    if (lane == 0) {
        xn[row] = s;
        atomicAdd(&cc[tgt[row]], 1);
    }
}

// ---------------------------------------------------------------------------
// Kernel 2: MFMA mining. G = X·X^T via bf16 split (hi+lo, 3 passes) with
// fp32 accumulate; d = clip(xn_i + xn_j - 2G, 0); per-row argmax(same-class)
// / argmin(diff-class) fused in-register on the C-layout.
//   MFMA D[r][c] = sum_k A[r][k]B[k][c]: A-operand = j-rows (from LDS),
//   B-operand = i-rows (register-resident per wave). Both operands load as
//   "lane holds row (lane&15), k = (lane>>4)*8 .. +7" -> short8 ds_read_b128.
//   C layout: col = lane&15 = i, row = (lane>>4)*4 + reg = j.  [m89/m91/m120]
// Block = 4 waves, owns 128 i-rows (wave: 2 x 16-row tiles). j split into
// S chunks across blocks (grid = 64*S) for occupancy; partials merged later.
// ---------------------------------------------------------------------------
__global__ __launch_bounds__(256) void mine_kernel(const float* __restrict__ x,
                                                   const int* __restrict__ tgt,
                                                   const float* __restrict__ xn,
                                                   int chunk_len,
                                                   float4* __restrict__ part) {
    __shared__ __align__(16) short Bh[64][136];  // +8 bf16 pad: 2-way reads (free)
    __shared__ __align__(16) short Bl[64][136];
    __shared__ float xnS[64];
    __shared__ int   tgtS[64];

    const int tid  = threadIdx.x;
    const int lane = tid & 63;
    const int w    = tid >> 6;      // wave 0..3
    const int m    = lane & 15;     // row-within-tile
    const int q    = lane >> 4;     // quad
    const int ib     = blockIdx.x & 63;
    const int chunk  = blockIdx.x >> 6;
    const int i0     = ib * 128;
    const int jbase0 = chunk * chunk_len;

    // ---- per-wave i-fragments (hi/lo bf16 limbs), once per kernel ----
    short8 aih[2][4], ail[2][4];
    float xni[2]; int ti[2];
    #pragma unroll
    for (int t = 0; t < 2; ++t) {
        const int irow = i0 + w * 32 + t * 16 + m;
        const float* xr = x + (size_t)irow * DIM;
        xni[t] = xn[irow];
        ti[t]  = tgt[irow];
        #pragma unroll
        for (int s = 0; s < 4; ++s) {
            const int k0 = s * 32 + q * 8;
            float4 va = *(const float4*)(xr + k0);
            float4 vb = *(const float4*)(xr + k0 + 4);
            float vv[8] = {va.x, va.y, va.z, va.w, vb.x, vb.y, vb.z, vb.w};
            short8 h, l;
            #pragma unroll
            for (int e = 0; e < 8; ++e) {
                unsigned u = __float_as_uint(vv[e]);
                h[e] = (short)(u >> 16);                              // hi = trunc bf16
                float lf = vv[e] - __uint_as_float(u & 0xffff0000u);  // exact residual
                l[e] = (short)(__float_as_uint(lf) >> 16);            // lo = trunc bf16
            }
            aih[t][s] = h; ail[t][s] = l;
        }
    }

    float mx[2] = {-FLT_MAX, -FLT_MAX}, mn[2] = {FLT_MAX, FLT_MAX};
    int mxj[2] = {0, 0}, mnj[2] = {0, 0};

    const int ntiles = chunk_len >> 6;
    for (int jt = 0; jt < ntiles; ++jt) {
        const int j0 = jbase0 + jt * 64;
        __syncthreads();
        // ---- stage 64 j-rows: fp32 -> packed bf16 hi/lo, 8B vector writes ----
        #pragma unroll
        for (int it = 0; it < 8; ++it) {
            const int f = tid + it * 256;
            const int row = f >> 5, kv = f & 31;
            float4 v = *(const float4*)(x + (size_t)(j0 + row) * DIM + kv * 4);
            unsigned u0 = __float_as_uint(v.x), u1 = __float_as_uint(v.y);
            unsigned u2 = __float_as_uint(v.z), u3 = __float_as_uint(v.w);
            unsigned h01 = (u0 >> 16) | (u1 & 0xffff0000u);
            unsigned h23 = (u2 >> 16) | (u3 & 0xffff0000u);
            float l0 = v.x - __uint_as_float(u0 & 0xffff0000u);
            float l1 = v.y - __uint_as_float(u1 & 0xffff0000u);
            float l2 = v.z - __uint_as_float(u2 & 0xffff0000u);
            float l3 = v.w - __uint_as_float(u3 & 0xffff0000u);
            unsigned p01 = (__float_as_uint(l0) >> 16) | (__float_as_uint(l1) & 0xffff0000u);
            unsigned p23 = (__float_as_uint(l2) >> 16) | (__float_as_uint(l3) & 0xffff0000u);
            *(uint2*)&Bh[row][kv * 4] = make_uint2(h01, h23);
            *(uint2*)&Bl[row][kv * 4] = make_uint2(p01, p23);
        }
        if (tid < 64) { xnS[tid] = xn[j0 + tid]; tgtS[tid] = tgt[j0 + tid]; }
        __syncthreads();

        #pragma unroll
        for (int jt4 = 0; jt4 < 4; ++jt4) {
            const int rb = jt4 * 16;
            floatx4 acc0 = {0.f, 0.f, 0.f, 0.f};
            floatx4 acc1 = {0.f, 0.f, 0.f, 0.f};
            #pragma unroll
            for (int s = 0; s < 4; ++s) {
                short8 jh = *(const short8*)&Bh[rb + m][s * 32 + q * 8];
                short8 jl = *(const short8*)&Bl[rb + m][s * 32 + q * 8];
                acc0 = __builtin_amdgcn_mfma_f32_16x16x32_bf16(jh, aih[0][s], acc0, 0, 0, 0);
                acc1 = __builtin_amdgcn_mfma_f32_16x16x32_bf16(jh, aih[1][s], acc1, 0, 0, 0);
                acc0 = __builtin_amdgcn_mfma_f32_16x16x32_bf16(jl, aih[0][s], acc0, 0, 0, 0);
                acc1 = __builtin_amdgcn_mfma_f32_16x16x32_bf16(jl, aih[1][s], acc1, 0, 0, 0);
                acc0 = __builtin_amdgcn_mfma_f32_16x16x32_bf16(jh, ail[0][s], acc0, 0, 0, 0);
                acc1 = __builtin_amdgcn_mfma_f32_16x16x32_bf16(jh, ail[1][s], acc1, 0, 0, 0);
            }
            float4 xnj4 = *(const float4*)&xnS[rb + q * 4];
            int4   tj4  = *(const int4*)&tgtS[rb + q * 4];
            const int jb = j0 + rb + q * 4;
            float xnj[4] = {xnj4.x, xnj4.y, xnj4.z, xnj4.w};
            int   tj[4]  = {tj4.x, tj4.y, tj4.z, tj4.w};
            #pragma unroll
            for (int t = 0; t < 2; ++t) {
                floatx4 acc = t ? acc1 : acc0;
                #pragma unroll
                for (int r = 0; r < 4; ++r) {
                    // j ascends per lane across r and tiles -> strict compare
                    // keeps first occurrence
                    float d = fmaxf(fmaf(-2.0f, acc[r], xni[t] + xnj[r]), 0.0f);
                    if (tj[r] == ti[t]) { if (d > mx[t]) { mx[t] = d; mxj[t] = jb + r; } }
                    else                { if (d < mn[t]) { mn[t] = d; mnj[t] = jb + r; } }
                }
            }
        }
    }

    // ---- cross-lane reduce: lanes l, l^16, l^32, l^48 share col i ----
    #pragma unroll
    for (int t = 0; t < 2; ++t) {
        #pragma unroll
        for (int off = 16; off <= 32; off <<= 1) {
            float omx = __shfl_xor(mx[t], off, 64);
            int   oj  = __shfl_xor(mxj[t], off, 64);
            if (omx > mx[t] || (omx == mx[t] && oj < mxj[t])) { mx[t] = omx; mxj[t] = oj; }
            float omn = __shfl_xor(mn[t], off, 64);
            int   on  = __shfl_xor(mnj[t], off, 64);
            if (omn < mn[t] || (omn == mn[t] && on < mnj[t])) { mn[t] = omn; mnj[t] = on; }
        }
        if (q == 0) {
            const int irow = i0 + w * 32 + t * 16 + m;
            part[(size_t)chunk * NROWS + irow] =
                make_float4(mx[t], __int_as_float(mxj[t]), mn[t], __int_as_float(mnj[t]));
        }
    }
}

// ---------------------------------------------------------------------------
// Kernel 2b: merge per-chunk partials (chunk ascending = j ascending; strict
// compare keeps smallest-j winner = first occurrence).
// ---------------------------------------------------------------------------
__global__ __launch_bounds__(256) void merge_kernel(const float4* __restrict__ part, int S,
                                                    int* __restrict__ g_pos,
                                                    int* __restrict__ g_neg) {
    const int r = blockIdx.x * 256 + threadIdx.x;
    float bx = -FLT_MAX, bn = FLT_MAX;
    int bxj = 0, bnj = 0;
    for (int c = 0; c < S; ++c) {
        float4 v = part[(size_t)c * NROWS + r];
        if (v.x > bx) { bx = v.x; bxj = __float_as_int(v.y); }
        if (v.z < bn) { bn = v.z; bnj = __float_as_int(v.w); }
    }
    g_pos[r] = bxj;
    g_neg[r] = bnj;
}

// ---------------------------------------------------------------------------
// Kernel 3: subset-position rank (ballot-popcount) + fused loss terms.
// ---------------------------------------------------------------------------
__global__ __launch_bounds__(256) void rank_loss_kernel(const float* __restrict__ x,
                                                        const int* __restrict__ tgt,
                                                        const int* __restrict__ g_pos,
                                                        const int* __restrict__ g_neg,
                                                        const int* __restrict__ cc,
                                                        float* __restrict__ gacc) {
    __shared__ float s_acc[7];
    const int tid = threadIdx.x;
    if (tid < 7) s_acc[tid] = 0.0f;
    __syncthreads();

    const int wid = tid >> 6, lane = tid & 63;
    const int r = blockIdx.x * 4 + wid;
    const int gp = g_pos[r], gn = g_neg[r], ti = tgt[r];
    const int lim = max(gp, gn);

    int cp = 0, cn = 0;
    for (int j0 = 0; j0 < lim; j0 += 64) {
        int j = j0 + lane;
        int tj = (j < lim) ? tgt[j] : ti;
        cp += __popcll(__ballot(j < gp && tj == ti));
        cn += __popcll(__ballot(j < gn && tj != ti));
    }
    const int pp = cp, pn = cn;

    const float2 a = *(const float2*)(x + (size_t)r * DIM + lane * 2);
    const float2 p = *(const float2*)(x + (size_t)pp * DIM + lane * 2);
    const float2 qv = *(const float2*)(x + (size_t)pn * DIM + lane * 2);
    float dap = (a.x - p.x) * (a.x - p.x) + (a.y - p.y) * (a.y - p.y);
    float dan = (a.x - qv.x) * (a.x - qv.x) + (a.y - qv.y) * (a.y - qv.y);
    float dpn = (p.x - qv.x) * (p.x - qv.x) + (p.y - qv.y) * (p.y - qv.y);
    float l1  = fabsf(a.x) + fabsf(a.y) + fabsf(p.x) + fabsf(p.y)
              + fabsf(qv.x) + fabsf(qv.y);
    #pragma unroll
    for (int off = 32; off > 0; off >>= 1) {
        dap += __shfl_xor(dap, off, 64);
        dan += __shfl_xor(dan, off, 64);
        dpn += __shfl_xor(dpn, off, 64);
        l1  += __shfl_xor(l1,  off, 64);
    }
    if (lane == 0) {
        int c = cc[ti];
        float vf = (c > 1 && (NROWS - c) >= 1) ? 1.0f : 0.0f;
        float tl = fmaxf(dap - dan + MARGIN, 0.0f) * vf;
        atomicAdd(&s_acc[0], tl);
        atomicAdd(&s_acc[1], (tl > 0.0f) ? 1.0f : 0.0f);
        atomicAdd(&s_acc[2], vf);
        atomicAdd(&s_acc[3], l1 * vf);
        atomicAdd(&s_acc[4], (dap - dan - dpn) * vf);
        atomicAdd(&s_acc[5], dap * vf);
        atomicAdd(&s_acc[6], dan * vf);
    }
    __syncthreads();
    if (tid < 7) atomicAdd(&gacc[tid], s_acc[tid]);
}

// ---------------------------------------------------------------------------
// Kernel 4: finalize 6 outputs.
// ---------------------------------------------------------------------------
__global__ void final_kernel(const float* __restrict__ g, float* __restrict__ out) {
    if (threadIdx.x == 0) {
        float tl = g[0], nz = g[1], vc = g[2], l1 = g[3];
        float pw = g[4], apS = g[5], anS = g[6];
        out[0] = (nz == 0.0f) ? (tl / vc) : (tl / fmaxf(nz, 1.0f));
        out[1] = (l1 / vc) * (1.0f / 3.0f);
        out[2] = fmaxf(pw / vc, 0.0f);
        out[3] = vc;
        out[4] = apS / vc;
        out[5] = anS / vc;
    }
}

extern "C" void kernel_launch(void* const* d_in, const int* in_sizes, int n_in,
                              void* d_out, int out_size, void* d_ws, size_t ws_size,
                              hipStream_t stream) {
    const float* x   = (const float*)d_in[0];
    const int*   tgt = (const int*)d_in[1];
    float* out = (float*)d_out;
    float* ws  = (float*)d_ws;

    float*  xn    = ws;                           // [0, N)
    int*    g_pos = (int*)(ws + NROWS);           // [N, 2N)
    int*    g_neg = (int*)(ws + 2 * NROWS);       // [2N, 3N)
    float*  gacc  = ws + 3 * NROWS;               // 8 floats
    int*    cc    = (int*)(ws + 3 * NROWS + 8);   // 64 ints (+ pad to 80)
    float4* part  = (float4*)(ws + 3 * NROWS + 80); // S*N float4, 16B-aligned

    int S = 16;
    while (S > 1 &&
           (size_t)(3 * NROWS + 80 + (size_t)S * NROWS * 4) * sizeof(float) > ws_size)
        S >>= 1;
    const int chunk_len = NROWS / S;

    hipMemsetAsync(gacc, 0, (8 + 64) * sizeof(float), stream);
    xn_cc_kernel<<<NROWS / 4, 256, 0, stream>>>(x, tgt, xn, cc);
    mine_kernel<<<64 * S, 256, 0, stream>>>(x, tgt, xn, chunk_len, part);
    merge_kernel<<<NROWS / 256, 256, 0, stream>>>(part, S, g_pos, g_neg);
    rank_loss_kernel<<<NROWS / 4, 256, 0, stream>>>(x, tgt, g_pos, g_neg, cc, gacc);
    final_kernel<<<1, 64, 0, stream>>>(gacc, out);
}

// Round 3
// 239.156 us; speedup vs baseline: 4.2258x; 1.2290x over previous
//
#include <hip/hip_runtime.h>
#include <float.h>
#include <stdint.h>

#define NROWS 8192
#define DIM 128
#define MARGIN 0.5f

typedef __attribute__((ext_vector_type(8))) short short8;   // 8 bf16 = 4 VGPRs
typedef __attribute__((ext_vector_type(4))) float floatx4;  // MFMA C/D

// async global->LDS, 16B per lane; LDS dest = wave-uniform base + lane*16
__device__ __forceinline__ void load_lds16(const void* g, void* l) {
    __builtin_amdgcn_global_load_lds(
        (const __attribute__((address_space(1))) unsigned int*)g,
        (__attribute__((address_space(3))) unsigned int*)l, 16, 0, 0);
}

__device__ __forceinline__ void split_pack(const float* vv, unsigned* h, unsigned* l) {
    #pragma unroll
    for (int e = 0; e < 4; ++e) {
        unsigned u0 = __float_as_uint(vv[2 * e]);
        unsigned u1 = __float_as_uint(vv[2 * e + 1]);
        h[e] = (u0 >> 16) | (u1 & 0xffff0000u);
        float l0 = vv[2 * e]     - __uint_as_float(u0 & 0xffff0000u);
        float l1 = vv[2 * e + 1] - __uint_as_float(u1 & 0xffff0000u);
        l[e] = (__float_as_uint(l0) >> 16) | (__float_as_uint(l1) & 0xffff0000u);
    }
}

// ---------------------------------------------------------------------------
// Kernel 1: xn[i] = dot(x[i], x[i]); class histogram cc[c].
// ---------------------------------------------------------------------------
__global__ __launch_bounds__(256) void xn_cc_kernel(const float* __restrict__ x,
                                                    const int* __restrict__ tgt,
                                                    float* __restrict__ xn,
                                                    int* __restrict__ cc) {
    const int wid  = threadIdx.x >> 6;
    const int lane = threadIdx.x & 63;
    const int row  = blockIdx.x * 4 + wid;
    const float2 v = *(const float2*)(x + (size_t)row * DIM + lane * 2);
    float s = v.x * v.x + v.y * v.y;
    #pragma unroll
    for (int off = 32; off > 0; off >>= 1) s += __shfl_xor(s, off, 64);
    if (lane == 0) {
        xn[row] = s;
        atomicAdd(&cc[tgt[row]], 1);
    }
}

// ---------------------------------------------------------------------------
// Kernel 1b: fragment-order bf16 hi/lo precompute (once).
// Layout: per (16-row tile jt, k-chunk s): 64 lanes x 16B of HI, then 64 x 16B
// of LO -> 2KB blocks, contiguous over (jt,s). Fragment = MFMA operand order:
// lane holds row lane&15, k = (lane>>4)*8 + e.  Writes 16B/lane coalesced.
// ---------------------------------------------------------------------------
__global__ __launch_bounds__(256) void frag_kernel(const float* __restrict__ x,
                                                   uint4* __restrict__ fragHL) {
    const int t = threadIdx.x, b = blockIdx.x;
    const int s = t >> 6, lane = t & 63;
    const int row = b * 16 + (lane & 15);
    const int k0  = s * 32 + (lane >> 4) * 8;
    const float* xr = x + (size_t)row * DIM + k0;
    float4 va = *(const float4*)xr, vb = *(const float4*)(xr + 4);
    float vv[8] = {va.x, va.y, va.z, va.w, vb.x, vb.y, vb.z, vb.w};
    unsigned h[4], l[4];
    split_pack(vv, h, l);
    uint4* base = fragHL + (size_t)(b * 4 + s) * 128;  // 2KB block
    base[lane]      = make_uint4(h[0], h[1], h[2], h[3]);
    base[64 + lane] = make_uint4(l[0], l[1], l[2], l[3]);
}

// ---------------------------------------------------------------------------
// Kernel 2: MFMA mining from precomputed fragments. Staging = pure DMA
// (global_load_lds x16B), zero conversion VALU, conflict-free ds_read_b128.
// Block = 4 waves, 128 i-rows; j split into S chunks across blocks.
// acc = mfma(jfrag, ifrag): C col=lane&15 = i, row = quad*4+reg = j.
// ---------------------------------------------------------------------------
__global__ __launch_bounds__(256, 4) void mine_kernel(const uint4* __restrict__ fragHL,
                                                      const int* __restrict__ tgt,
                                                      const float* __restrict__ xn,
                                                      int chunk_len,
                                                      float4* __restrict__ part) {
    __shared__ __align__(16) uint4 Sb[2048];   // 32KB: 16 (st,s) blocks x 2KB
    __shared__ float xnS[64];
    __shared__ int   tgtS[64];

    const int tid  = threadIdx.x;
    const int lane = tid & 63;
    const int w    = tid >> 6;
    const int m    = lane & 15;
    const int q    = lane >> 4;
    const int ib     = blockIdx.x & 63;
    const int chunk  = blockIdx.x >> 6;
    const int i0     = ib * 128;
    const int jbase0 = chunk * chunk_len;

    // i-fragments from global frag array (coalesced 16B/lane), persist in regs
    short8 aih[2][4], ail[2][4];
    float xni[2]; int ti[2];
    #pragma unroll
    for (int t = 0; t < 2; ++t) {
        const int irow = i0 + w * 32 + t * 16 + m;
        xni[t] = xn[irow];
        ti[t]  = tgt[irow];
        const int itile = (i0 >> 4) + w * 2 + t;
        #pragma unroll
        for (int s = 0; s < 4; ++s) {
            const uint4* fb = fragHL + (size_t)(itile * 4 + s) * 128;
            aih[t][s] = *(const short8*)&fb[lane];
            ail[t][s] = *(const short8*)&fb[64 + lane];
        }
    }

    float mx[2] = {-FLT_MAX, -FLT_MAX}, mn[2] = {FLT_MAX, FLT_MAX};
    int mxj[2] = {0, 0}, mnj[2] = {0, 0};

    const int ntiles = chunk_len >> 6;
    for (int jt = 0; jt < ntiles; ++jt) {
        const int j0 = jbase0 + jt * 64;
        __syncthreads();
        // stage 64 j-rows' fragments: linear 32KB DMA copy
        const char* g = (const char*)(fragHL + (size_t)(j0 >> 4) * 512);
        #pragma unroll
        for (int it = 0; it < 8; ++it)
            load_lds16(g + it * 4096 + tid * 16,
                       (char*)Sb + it * 4096 + w * 1024);
        if (tid < 64) { xnS[tid] = xn[j0 + tid]; tgtS[tid] = tgt[j0 + tid]; }
        __syncthreads();   // drains vmcnt (global_load_lds) + lds writes

        #pragma unroll
        for (int st = 0; st < 4; ++st) {
            floatx4 acc0 = {0.f, 0.f, 0.f, 0.f};
            floatx4 acc1 = {0.f, 0.f, 0.f, 0.f};
            #pragma unroll
            for (int s = 0; s < 4; ++s) {
                const uint4* sb = Sb + (st * 4 + s) * 128;
                short8 jh = *(const short8*)&sb[lane];
                short8 jl = *(const short8*)&sb[64 + lane];
                acc0 = __builtin_amdgcn_mfma_f32_16x16x32_bf16(jh, aih[0][s], acc0, 0, 0, 0);
                acc1 = __builtin_amdgcn_mfma_f32_16x16x32_bf16(jh, aih[1][s], acc1, 0, 0, 0);
                acc0 = __builtin_amdgcn_mfma_f32_16x16x32_bf16(jl, aih[0][s], acc0, 0, 0, 0);
                acc1 = __builtin_amdgcn_mfma_f32_16x16x32_bf16(jl, aih[1][s], acc1, 0, 0, 0);
                acc0 = __builtin_amdgcn_mfma_f32_16x16x32_bf16(jh, ail[0][s], acc0, 0, 0, 0);
                acc1 = __builtin_amdgcn_mfma_f32_16x16x32_bf16(jh, ail[1][s], acc1, 0, 0, 0);
            }
            float4 xnj4 = *(const float4*)&xnS[st * 16 + q * 4];
            int4   tj4  = *(const int4*)&tgtS[st * 16 + q * 4];
            const int jb = j0 + st * 16 + q * 4;
            float xnj[4] = {xnj4.x, xnj4.y, xnj4.z, xnj4.w};
            int   tj[4]  = {tj4.x, tj4.y, tj4.z, tj4.w};
            #pragma unroll
            for (int t = 0; t < 2; ++t) {
                floatx4 acc = t ? acc1 : acc0;
                #pragma unroll
                for (int r = 0; r < 4; ++r) {
                    // j ascends per lane -> strict compare keeps first occurrence
                    float d = fmaxf(fmaf(-2.0f, acc[r], xni[t] + xnj[r]), 0.0f);
                    if (tj[r] == ti[t]) { if (d > mx[t]) { mx[t] = d; mxj[t] = jb + r; } }
                    else                { if (d < mn[t]) { mn[t] = d; mnj[t] = jb + r; } }
                }
            }
        }
    }

    #pragma unroll
    for (int t = 0; t < 2; ++t) {
        #pragma unroll
        for (int off = 16; off <= 32; off <<= 1) {
            float omx = __shfl_xor(mx[t], off, 64);
            int   oj  = __shfl_xor(mxj[t], off, 64);
            if (omx > mx[t] || (omx == mx[t] && oj < mxj[t])) { mx[t] = omx; mxj[t] = oj; }
            float omn = __shfl_xor(mn[t], off, 64);
            int   on  = __shfl_xor(mnj[t], off, 64);
            if (omn < mn[t] || (omn == mn[t] && on < mnj[t])) { mn[t] = omn; mnj[t] = on; }
        }
        if (q == 0) {
            const int irow = i0 + w * 32 + t * 16 + m;
            part[(size_t)chunk * NROWS + irow] =
                make_float4(mx[t], __int_as_float(mxj[t]), mn[t], __int_as_float(mnj[t]));
        }
    }
}

// ---------------------------------------------------------------------------
// Fallback mine (in-kernel conversion) for small ws_size — R2 version.
// ---------------------------------------------------------------------------
__global__ __launch_bounds__(256) void mine_conv_kernel(const float* __restrict__ x,
                                                        const int* __restrict__ tgt,
                                                        const float* __restrict__ xn,
                                                        int chunk_len,
                                                        float4* __restrict__ part) {
    __shared__ __align__(16) short Bh[64][136];
    __shared__ __align__(16) short Bl[64][136];
    __shared__ float xnS[64];
    __shared__ int   tgtS[64];

    const int tid  = threadIdx.x;
    const int lane = tid & 63;
    const int w    = tid >> 6;
    const int m    = lane & 15;
    const int q    = lane >> 4;
    const int ib     = blockIdx.x & 63;
    const int chunk  = blockIdx.x >> 6;
    const int i0     = ib * 128;
    const int jbase0 = chunk * chunk_len;

    short8 aih[2][4], ail[2][4];
    float xni[2]; int ti[2];
    #pragma unroll
    for (int t = 0; t < 2; ++t) {
        const int irow = i0 + w * 32 + t * 16 + m;
        const float* xr = x + (size_t)irow * DIM;
        xni[t] = xn[irow]; ti[t] = tgt[irow];
        #pragma unroll
        for (int s = 0; s < 4; ++s) {
            const int k0 = s * 32 + q * 8;
            float4 va = *(const float4*)(xr + k0);
            float4 vb = *(const float4*)(xr + k0 + 4);
            float vv[8] = {va.x, va.y, va.z, va.w, vb.x, vb.y, vb.z, vb.w};
            unsigned h[4], l[4];
            split_pack(vv, h, l);
            aih[t][s] = *(short8*)h; ail[t][s] = *(short8*)l;
        }
    }

    float mx[2] = {-FLT_MAX, -FLT_MAX}, mn[2] = {FLT_MAX, FLT_MAX};
    int mxj[2] = {0, 0}, mnj[2] = {0, 0};

    const int ntiles = chunk_len >> 6;
    for (int jt = 0; jt < ntiles; ++jt) {
        const int j0 = jbase0 + jt * 64;
        __syncthreads();
        #pragma unroll
        for (int it = 0; it < 8; ++it) {
            const int f = tid + it * 256;
            const int row = f >> 5, kv = f & 31;
            float4 v = *(const float4*)(x + (size_t)(j0 + row) * DIM + kv * 4);
            float vv[4] = {v.x, v.y, v.z, v.w};
            float vv8[8] = {vv[0], vv[1], vv[2], vv[3], 0, 0, 0, 0};
            unsigned h[4], l[4];
            split_pack(vv8, h, l);
            *(uint2*)&Bh[row][kv * 4] = make_uint2(h[0], h[1]);
            *(uint2*)&Bl[row][kv * 4] = make_uint2(l[0], l[1]);
        }
        if (tid < 64) { xnS[tid] = xn[j0 + tid]; tgtS[tid] = tgt[j0 + tid]; }
        __syncthreads();

        #pragma unroll
        for (int st = 0; st < 4; ++st) {
            const int rb = st * 16;
            floatx4 acc0 = {0.f, 0.f, 0.f, 0.f};
            floatx4 acc1 = {0.f, 0.f, 0.f, 0.f};
            #pragma unroll
            for (int s = 0; s < 4; ++s) {
                short8 jh = *(const short8*)&Bh[rb + m][s * 32 + q * 8];
                short8 jl = *(const short8*)&Bl[rb + m][s * 32 + q * 8];
                acc0 = __builtin_amdgcn_mfma_f32_16x16x32_bf16(jh, aih[0][s], acc0, 0, 0, 0);
                acc1 = __builtin_amdgcn_mfma_f32_16x16x32_bf16(jh, aih[1][s], acc1, 0, 0, 0);
                acc0 = __builtin_amdgcn_mfma_f32_16x16x32_bf16(jl, aih[0][s], acc0, 0, 0, 0);
                acc1 = __builtin_amdgcn_mfma_f32_16x16x32_bf16(jl, aih[1][s], acc1, 0, 0, 0);
                acc0 = __builtin_amdgcn_mfma_f32_16x16x32_bf16(jh, ail[0][s], acc0, 0, 0, 0);
                acc1 = __builtin_amdgcn_mfma_f32_16x16x32_bf16(jh, ail[1][s], acc1, 0, 0, 0);
            }
            float4 xnj4 = *(const float4*)&xnS[rb + q * 4];
            int4   tj4  = *(const int4*)&tgtS[rb + q * 4];
            const int jb = j0 + rb + q * 4;
            float xnj[4] = {xnj4.x, xnj4.y, xnj4.z, xnj4.w};
            int   tj[4]  = {tj4.x, tj4.y, tj4.z, tj4.w};
            #pragma unroll
            for (int t = 0; t < 2; ++t) {
                floatx4 acc = t ? acc1 : acc0;
                #pragma unroll
                for (int r = 0; r < 4; ++r) {
                    float d = fmaxf(fmaf(-2.0f, acc[r], xni[t] + xnj[r]), 0.0f);
                    if (tj[r] == ti[t]) { if (d > mx[t]) { mx[t] = d; mxj[t] = jb + r; } }
                    else                { if (d < mn[t]) { mn[t] = d; mnj[t] = jb + r; } }
                }
            }
        }
    }

    #pragma unroll
    for (int t = 0; t < 2; ++t) {
        #pragma unroll
        for (int off = 16; off <= 32; off <<= 1) {
            float omx = __shfl_xor(mx[t], off, 64);
            int   oj  = __shfl_xor(mxj[t], off, 64);
            if (omx > mx[t] || (omx == mx[t] && oj < mxj[t])) { mx[t] = omx; mxj[t] = oj; }
            float omn = __shfl_xor(mn[t], off, 64);
            int   on  = __shfl_xor(mnj[t], off, 64);
            if (omn < mn[t] || (omn == mn[t] && on < mnj[t])) { mn[t] = omn; mnj[t] = on; }
        }
        if (q == 0) {
            const int irow = i0 + w * 32 + t * 16 + m;
            part[(size_t)chunk * NROWS + irow] =
                make_float4(mx[t], __int_as_float(mxj[t]), mn[t], __int_as_float(mnj[t]));
        }
    }
}

// ---------------------------------------------------------------------------
// Kernel 3: fused chunk-merge + subset-position rank + loss terms.
// Wave per row: lanes 0..S-1 hold chunk partials, shfl-merge (tie: smaller j),
// then ballot-popcount rank, then reduced loss terms.
// ---------------------------------------------------------------------------
__global__ __launch_bounds__(256) void rank_loss_kernel(const float* __restrict__ x,
                                                        const int* __restrict__ tgt,
                                                        const float4* __restrict__ part,
                                                        int S,
                                                        const int* __restrict__ cc,
                                                        float* __restrict__ gacc) {
    __shared__ float s_acc[7];
    const int tid = threadIdx.x;
    if (tid < 7) s_acc[tid] = 0.0f;
    __syncthreads();

    const int wid = tid >> 6, lane = tid & 63;
    const int r = blockIdx.x * 4 + wid;
    const int ti = tgt[r];

    // merge chunk partials (chunk = lane; ascending chunk = ascending j)
    float bx = -FLT_MAX, bn = FLT_MAX;
    int bxj = 0x7fffffff, bnj = 0x7fffffff;
    if (lane < S) {
        float4 v = part[(size_t)lane * NROWS + r];
        bx = v.x; bxj = __float_as_int(v.y);
        bn = v.z; bnj = __float_as_int(v.w);
    }
    #pragma unroll
    for (int off = 1; off <= 8; off <<= 1) {
        float ox = __shfl_xor(bx, off, 64);
        int   oj = __shfl_xor(bxj, off, 64);
        if (ox > bx || (ox == bx && oj < bxj)) { bx = ox; bxj = oj; }
        float on = __shfl_xor(bn, off, 64);
        int   onj = __shfl_xor(bnj, off, 64);
        if (on < bn || (on == bn && onj < bnj)) { bn = on; bnj = onj; }
    }
    const int gp = __shfl(bxj, 0, 64);
    const int gn = __shfl(bnj, 0, 64);
    const int lim = max(gp, gn);

    int cp = 0, cn = 0;
    for (int j0 = 0; j0 < lim; j0 += 64) {
        int j = j0 + lane;
        int tj = (j < lim) ? tgt[j] : ti;
        cp += __popcll(__ballot(j < gp && tj == ti));
        cn += __popcll(__ballot(j < gn && tj != ti));
    }
    const int pp = cp, pn = cn;

    const float2 a  = *(const float2*)(x + (size_t)r  * DIM + lane * 2);
    const float2 p  = *(const float2*)(x + (size_t)pp * DIM + lane * 2);
    const float2 qv = *(const float2*)(x + (size_t)pn * DIM + lane * 2);
    float dap = (a.x - p.x) * (a.x - p.x) + (a.y - p.y) * (a.y - p.y);
    float dan = (a.x - qv.x) * (a.x - qv.x) + (a.y - qv.y) * (a.y - qv.y);
    float dpn = (p.x - qv.x) * (p.x - qv.x) + (p.y - qv.y) * (p.y - qv.y);
    float l1  = fabsf(a.x) + fabsf(a.y) + fabsf(p.x) + fabsf(p.y)
              + fabsf(qv.x) + fabsf(qv.y);
    #pragma unroll
    for (int off = 32; off > 0; off >>= 1) {
        dap += __shfl_xor(dap, off, 64);
        dan += __shfl_xor(dan, off, 64);
        dpn += __shfl_xor(dpn, off, 64);
        l1  += __shfl_xor(l1,  off, 64);
    }
    if (lane == 0) {
        int c = cc[ti];
        float vf = (c > 1 && (NROWS - c) >= 1) ? 1.0f : 0.0f;
        float tl = fmaxf(dap - dan + MARGIN, 0.0f) * vf;
        atomicAdd(&s_acc[0], tl);
        atomicAdd(&s_acc[1], (tl > 0.0f) ? 1.0f : 0.0f);
        atomicAdd(&s_acc[2], vf);
        atomicAdd(&s_acc[3], l1 * vf);
        atomicAdd(&s_acc[4], (dap - dan - dpn) * vf);
        atomicAdd(&s_acc[5], dap * vf);
        atomicAdd(&s_acc[6], dan * vf);
    }
    __syncthreads();
    if (tid < 7) atomicAdd(&gacc[tid], s_acc[tid]);
}

__global__ void final_kernel(const float* __restrict__ g, float* __restrict__ out) {
    if (threadIdx.x == 0) {
        float tl = g[0], nz = g[1], vc = g[2], l1 = g[3];
        float pw = g[4], apS = g[5], anS = g[6];
        out[0] = (nz == 0.0f) ? (tl / vc) : (tl / fmaxf(nz, 1.0f));
        out[1] = (l1 / vc) * (1.0f / 3.0f);
        out[2] = fmaxf(pw / vc, 0.0f);
        out[3] = vc;
        out[4] = apS / vc;
        out[5] = anS / vc;
    }
}

extern "C" void kernel_launch(void* const* d_in, const int* in_sizes, int n_in,
                              void* d_out, int out_size, void* d_ws, size_t ws_size,
                              hipStream_t stream) {
    const float* x   = (const float*)d_in[0];
    const int*   tgt = (const int*)d_in[1];
    float* out = (float*)d_out;
    char*  ws  = (char*)d_ws;

    const size_t fragBytes = (size_t)NROWS * DIM * 2 * 2;  // 4MB hi+lo bf16
    const size_t auxBytes  = (size_t)NROWS * 4 + 8 * 4 + 64 * 4;  // xn+gacc+cc

    // frag path needs frag + aux + S*N*16
    int S = 16;
    bool fragpath = ws_size >= fragBytes + auxBytes + (size_t)4 * NROWS * 16;
    if (fragpath)
        while (ws_size < fragBytes + auxBytes + (size_t)S * NROWS * 16) S >>= 1;
    else {
        S = 16;
        while (S > 1 && ws_size < auxBytes + (size_t)S * NROWS * 16) S >>= 1;
    }
    const int chunk_len = NROWS / S;

    size_t off = fragpath ? fragBytes : 0;
    uint4*  fragHL = (uint4*)ws;
    float*  xn   = (float*)(ws + off);           off += (size_t)NROWS * 4;
    float*  gacc = (float*)(ws + off);           off += 8 * 4;
    int*    cc   = (int*)(ws + off);             off += 64 * 4;
    float4* part = (float4*)(ws + off);

    hipMemsetAsync(gacc, 0, (8 + 64) * sizeof(float), stream);
    xn_cc_kernel<<<NROWS / 4, 256, 0, stream>>>(x, tgt, xn, cc);
    if (fragpath) {
        frag_kernel<<<NROWS / 16, 256, 0, stream>>>(x, fragHL);
        mine_kernel<<<64 * S, 256, 0, stream>>>(fragHL, tgt, xn, chunk_len, part);
    } else {
        mine_conv_kernel<<<64 * S, 256, 0, stream>>>(x, tgt, xn, chunk_len, part);
    }
    rank_loss_kernel<<<NROWS / 4, 256, 0, stream>>>(x, tgt, part, S, cc, gacc);
    final_kernel<<<1, 64, 0, stream>>>(gacc, out);
}

// Round 4
// 221.131 us; speedup vs baseline: 4.5703x; 1.0815x over previous
//
#include <hip/hip_runtime.h>
#include <float.h>
#include <stdint.h>

#define NROWS 8192
#define DIM 128
#define MARGIN 0.5f
#define NCHUNK (NROWS / 64)   // 128 64-row chunks for the class-prefix table

typedef __attribute__((ext_vector_type(8))) short short8;   // 8 bf16 = 4 VGPRs
typedef __attribute__((ext_vector_type(4))) float floatx4;  // MFMA C/D

// async global->LDS, 16B per lane; LDS dest = wave-uniform base + lane*16
__device__ __forceinline__ void load_lds16(const void* g, void* l) {
    __builtin_amdgcn_global_load_lds(
        (const __attribute__((address_space(1))) unsigned int*)g,
        (__attribute__((address_space(3))) unsigned int*)l, 16, 0, 0);
}

__device__ __forceinline__ void split_pack(const float* vv, unsigned* h, unsigned* l) {
    #pragma unroll
    for (int e = 0; e < 4; ++e) {
        unsigned u0 = __float_as_uint(vv[2 * e]);
        unsigned u1 = __float_as_uint(vv[2 * e + 1]);
        h[e] = (u0 >> 16) | (u1 & 0xffff0000u);
        float l0 = vv[2 * e]     - __uint_as_float(u0 & 0xffff0000u);
        float l1 = vv[2 * e + 1] - __uint_as_float(u1 & 0xffff0000u);
        l[e] = (__float_as_uint(l0) >> 16) | (__float_as_uint(l1) & 0xffff0000u);
    }
}

// ---------------------------------------------------------------------------
// Kernel 1: xn[i] = dot(x[i], x[i]); class histogram cc[c].
// ---------------------------------------------------------------------------
__global__ __launch_bounds__(256) void xn_cc_kernel(const float* __restrict__ x,
                                                    const int* __restrict__ tgt,
                                                    float* __restrict__ xn,
                                                    int* __restrict__ cc) {
    const int wid  = threadIdx.x >> 6;
    const int lane = threadIdx.x & 63;
    const int row  = blockIdx.x * 4 + wid;
    const float2 v = *(const float2*)(x + (size_t)row * DIM + lane * 2);
    float s = v.x * v.x + v.y * v.y;
    #pragma unroll
    for (int off = 32; off > 0; off >>= 1) s += __shfl_xor(s, off, 64);
    if (lane == 0) {
        xn[row] = s;
        atomicAdd(&cc[tgt[row]], 1);
    }
}

// ---------------------------------------------------------------------------
// Kernel 1b: class-prefix table. pre[k*64+c] = #{ j < 64k : tgt[j]==c }.
// One block: LDS-atomic per-chunk histogram, then 64-lane serial scan over
// 128 chunks (cnt[k][tid] reads are 2-way bank aliased = free).
// ---------------------------------------------------------------------------
__global__ __launch_bounds__(256) void prefix_kernel(const int* __restrict__ tgt,
                                                     int* __restrict__ pre) {
    __shared__ int cnt[NCHUNK][64];   // 32KB
    const int tid = threadIdx.x;
    for (int f = tid; f < NCHUNK * 64; f += 256) ((int*)cnt)[f] = 0;
    __syncthreads();
    for (int j = tid; j < NROWS; j += 256) atomicAdd(&cnt[j >> 6][tgt[j]], 1);
    __syncthreads();
    if (tid < 64) {
        int run = 0;
        for (int k = 0; k < NCHUNK; ++k) {
            pre[k * 64 + tid] = run;
            run += cnt[k][tid];
        }
    }
}

// ---------------------------------------------------------------------------
// Kernel 1c: fragment-order bf16 hi/lo precompute (separate H and L arrays).
// Per 16-row tile b, k-chunk s: 64 lanes x 16B -> 1KB block at (b*4+s)*1KB.
// Fragment order: lane holds row lane&15, k = (lane>>4)*8 + e.
// ---------------------------------------------------------------------------
__global__ __launch_bounds__(256) void frag_kernel(const float* __restrict__ x,
                                                   uint4* __restrict__ fragH,
                                                   uint4* __restrict__ fragL) {
    const int t = threadIdx.x, b = blockIdx.x;
    const int s = t >> 6, lane = t & 63;
    const int row = b * 16 + (lane & 15);
    const int k0  = s * 32 + (lane >> 4) * 8;
    const float* xr = x + (size_t)row * DIM + k0;
    float4 va = *(const float4*)xr, vb = *(const float4*)(xr + 4);
    float vv[8] = {va.x, va.y, va.z, va.w, vb.x, vb.y, vb.z, vb.w};
    unsigned h[4], l[4];
    split_pack(vv, h, l);
    fragH[(size_t)(b * 4 + s) * 64 + lane] = make_uint4(h[0], h[1], h[2], h[3]);
    fragL[(size_t)(b * 4 + s) * 64 + lane] = make_uint4(l[0], l[1], l[2], l[3]);
}

// ---------------------------------------------------------------------------
// Kernel 2: MFMA mining, 2-pass split: G = (i_hi + i_lo) · j_hi.
// j-side stages HI limb only (16KB/tile DMA via global_load_lds x16B).
// Block = 4 waves, 128 i-rows; j split into S chunks across blocks.
// acc = mfma(jfrag, ifrag): C col=lane&15 = i, row = quad*4+reg = j.
// ---------------------------------------------------------------------------
__global__ __launch_bounds__(256, 4) void mine_kernel(const uint4* __restrict__ fragH,
                                                      const uint4* __restrict__ fragL,
                                                      const int* __restrict__ tgt,
                                                      const float* __restrict__ xn,
                                                      int chunk_len,
                                                      float4* __restrict__ part) {
    __shared__ __align__(16) uint4 Sb[1024];   // 16KB: 16 (st,s) blocks x 1KB
    __shared__ float xnS[64];
    __shared__ int   tgtS[64];

    const int tid  = threadIdx.x;
    const int lane = tid & 63;
    const int w    = tid >> 6;
    const int m    = lane & 15;
    const int q    = lane >> 4;
    const int ib     = blockIdx.x & 63;
    const int chunk  = blockIdx.x >> 6;
    const int i0     = ib * 128;
    const int jbase0 = chunk * chunk_len;

    // i-fragments (hi + lo), coalesced 16B/lane, persist in regs
    short8 aih[2][4], ail[2][4];
    float xni[2]; int ti[2];
    #pragma unroll
    for (int t = 0; t < 2; ++t) {
        const int irow = i0 + w * 32 + t * 16 + m;
        xni[t] = xn[irow];
        ti[t]  = tgt[irow];
        const int itile = (i0 >> 4) + w * 2 + t;
        #pragma unroll
        for (int s = 0; s < 4; ++s) {
            aih[t][s] = *(const short8*)&fragH[(size_t)(itile * 4 + s) * 64 + lane];
            ail[t][s] = *(const short8*)&fragL[(size_t)(itile * 4 + s) * 64 + lane];
        }
    }

    float mx[2] = {-FLT_MAX, -FLT_MAX}, mn[2] = {FLT_MAX, FLT_MAX};
    int mxj[2] = {0, 0}, mnj[2] = {0, 0};

    const int ntiles = chunk_len >> 6;
    for (int jt = 0; jt < ntiles; ++jt) {
        const int j0 = jbase0 + jt * 64;
        __syncthreads();
        // stage 64 j-rows' HI fragments: linear 16KB DMA copy
        const char* g = (const char*)(fragH + (size_t)(j0 >> 4) * 256);
        #pragma unroll
        for (int it = 0; it < 4; ++it)
            load_lds16(g + it * 4096 + tid * 16,
                       (char*)Sb + it * 4096 + w * 1024);
        if (tid < 64) { xnS[tid] = xn[j0 + tid]; tgtS[tid] = tgt[j0 + tid]; }
        __syncthreads();   // drains vmcnt (global_load_lds) + lds writes

        #pragma unroll
        for (int st = 0; st < 4; ++st) {
            floatx4 acc0 = {0.f, 0.f, 0.f, 0.f};
            floatx4 acc1 = {0.f, 0.f, 0.f, 0.f};
            #pragma unroll
            for (int s = 0; s < 4; ++s) {
                short8 jh = *(const short8*)&Sb[(st * 4 + s) * 64 + lane];
                acc0 = __builtin_amdgcn_mfma_f32_16x16x32_bf16(jh, aih[0][s], acc0, 0, 0, 0);
                acc1 = __builtin_amdgcn_mfma_f32_16x16x32_bf16(jh, aih[1][s], acc1, 0, 0, 0);
                acc0 = __builtin_amdgcn_mfma_f32_16x16x32_bf16(jh, ail[0][s], acc0, 0, 0, 0);
                acc1 = __builtin_amdgcn_mfma_f32_16x16x32_bf16(jh, ail[1][s], acc1, 0, 0, 0);
            }
            float4 xnj4 = *(const float4*)&xnS[st * 16 + q * 4];
            int4   tj4  = *(const int4*)&tgtS[st * 16 + q * 4];
            const int jb = j0 + st * 16 + q * 4;
            float xnj[4] = {xnj4.x, xnj4.y, xnj4.z, xnj4.w};
            int   tj[4]  = {tj4.x, tj4.y, tj4.z, tj4.w};
            #pragma unroll
            for (int t = 0; t < 2; ++t) {
                floatx4 acc = t ? acc1 : acc0;
                #pragma unroll
                for (int r = 0; r < 4; ++r) {
                    // j ascends per lane -> strict compare keeps first occurrence
                    float d = fmaxf(fmaf(-2.0f, acc[r], xni[t] + xnj[r]), 0.0f);
                    if (tj[r] == ti[t]) { if (d > mx[t]) { mx[t] = d; mxj[t] = jb + r; } }
                    else                { if (d < mn[t]) { mn[t] = d; mnj[t] = jb + r; } }
                }
            }
        }
    }

    #pragma unroll
    for (int t = 0; t < 2; ++t) {
        #pragma unroll
        for (int off = 16; off <= 32; off <<= 1) {
            float omx = __shfl_xor(mx[t], off, 64);
            int   oj  = __shfl_xor(mxj[t], off, 64);
            if (omx > mx[t] || (omx == mx[t] && oj < mxj[t])) { mx[t] = omx; mxj[t] = oj; }
            float omn = __shfl_xor(mn[t], off, 64);
            int   on  = __shfl_xor(mnj[t], off, 64);
            if (omn < mn[t] || (omn == mn[t] && on < mnj[t])) { mn[t] = omn; mnj[t] = on; }
        }
        if (q == 0) {
            const int irow = i0 + w * 32 + t * 16 + m;
            part[(size_t)chunk * NROWS + irow] =
                make_float4(mx[t], __int_as_float(mxj[t]), mn[t], __int_as_float(mnj[t]));
        }
    }
}

// ---------------------------------------------------------------------------
// Fallback mine (in-kernel conversion, 3-pass) for small ws_size.
// ---------------------------------------------------------------------------
__global__ __launch_bounds__(256) void mine_conv_kernel(const float* __restrict__ x,
                                                        const int* __restrict__ tgt,
                                                        const float* __restrict__ xn,
                                                        int chunk_len,
                                                        float4* __restrict__ part) {
    __shared__ __align__(16) short Bh[64][136];
    __shared__ __align__(16) short Bl[64][136];
    __shared__ float xnS[64];
    __shared__ int   tgtS[64];

    const int tid  = threadIdx.x;
    const int lane = tid & 63;
    const int w    = tid >> 6;
    const int m    = lane & 15;
    const int q    = lane >> 4;
    const int ib     = blockIdx.x & 63;
    const int chunk  = blockIdx.x >> 6;
    const int i0     = ib * 128;
    const int jbase0 = chunk * chunk_len;

    short8 aih[2][4], ail[2][4];
    float xni[2]; int ti[2];
    #pragma unroll
    for (int t = 0; t < 2; ++t) {
        const int irow = i0 + w * 32 + t * 16 + m;
        const float* xr = x + (size_t)irow * DIM;
        xni[t] = xn[irow]; ti[t] = tgt[irow];
        #pragma unroll
        for (int s = 0; s < 4; ++s) {
            const int k0 = s * 32 + q * 8;
            float4 va = *(const float4*)(xr + k0);
            float4 vb = *(const float4*)(xr + k0 + 4);
            float vv[8] = {va.x, va.y, va.z, va.w, vb.x, vb.y, vb.z, vb.w};
            unsigned h[4], l[4];
            split_pack(vv, h, l);
            aih[t][s] = *(short8*)h; ail[t][s] = *(short8*)l;
        }
    }

    float mx[2] = {-FLT_MAX, -FLT_MAX}, mn[2] = {FLT_MAX, FLT_MAX};
    int mxj[2] = {0, 0}, mnj[2] = {0, 0};

    const int ntiles = chunk_len >> 6;
    for (int jt = 0; jt < ntiles; ++jt) {
        const int j0 = jbase0 + jt * 64;
        __syncthreads();
        #pragma unroll
        for (int it = 0; it < 8; ++it) {
            const int f = tid + it * 256;
            const int row = f >> 5, kv = f & 31;
            float4 v = *(const float4*)(x + (size_t)(j0 + row) * DIM + kv * 4);
            float vv8[8] = {v.x, v.y, v.z, v.w, 0, 0, 0, 0};
            unsigned h[4], l[4];
            split_pack(vv8, h, l);
            *(uint2*)&Bh[row][kv * 4] = make_uint2(h[0], h[1]);
            *(uint2*)&Bl[row][kv * 4] = make_uint2(l[0], l[1]);
        }
        if (tid < 64) { xnS[tid] = xn[j0 + tid]; tgtS[tid] = tgt[j0 + tid]; }
        __syncthreads();

        #pragma unroll
        for (int st = 0; st < 4; ++st) {
            const int rb = st * 16;
            floatx4 acc0 = {0.f, 0.f, 0.f, 0.f};
            floatx4 acc1 = {0.f, 0.f, 0.f, 0.f};
            #pragma unroll
            for (int s = 0; s < 4; ++s) {
                short8 jh = *(const short8*)&Bh[rb + m][s * 32 + q * 8];
                short8 jl = *(const short8*)&Bl[rb + m][s * 32 + q * 8];
                acc0 = __builtin_amdgcn_mfma_f32_16x16x32_bf16(jh, aih[0][s], acc0, 0, 0, 0);
                acc1 = __builtin_amdgcn_mfma_f32_16x16x32_bf16(jh, aih[1][s], acc1, 0, 0, 0);
                acc0 = __builtin_amdgcn_mfma_f32_16x16x32_bf16(jl, aih[0][s], acc0, 0, 0, 0);
                acc1 = __builtin_amdgcn_mfma_f32_16x16x32_bf16(jl, aih[1][s], acc1, 0, 0, 0);
                acc0 = __builtin_amdgcn_mfma_f32_16x16x32_bf16(jh, ail[0][s], acc0, 0, 0, 0);
                acc1 = __builtin_amdgcn_mfma_f32_16x16x32_bf16(jh, ail[1][s], acc1, 0, 0, 0);
            }
            float4 xnj4 = *(const float4*)&xnS[rb + q * 4];
            int4   tj4  = *(const int4*)&tgtS[rb + q * 4];
            const int jb = j0 + rb + q * 4;
            float xnj[4] = {xnj4.x, xnj4.y, xnj4.z, xnj4.w};
            int   tj[4]  = {tj4.x, tj4.y, tj4.z, tj4.w};
            #pragma unroll
            for (int t = 0; t < 2; ++t) {
                floatx4 acc = t ? acc1 : acc0;
                #pragma unroll
                for (int r = 0; r < 4; ++r) {
                    float d = fmaxf(fmaf(-2.0f, acc[r], xni[t] + xnj[r]), 0.0f);
                    if (tj[r] == ti[t]) { if (d > mx[t]) { mx[t] = d; mxj[t] = jb + r; } }
                    else                { if (d < mn[t]) { mn[t] = d; mnj[t] = jb + r; } }
                }
            }
        }
    }

    #pragma unroll
    for (int t = 0; t < 2; ++t) {
        #pragma unroll
        for (int off = 16; off <= 32; off <<= 1) {
            float omx = __shfl_xor(mx[t], off, 64);
            int   oj  = __shfl_xor(mxj[t], off, 64);
            if (omx > mx[t] || (omx == mx[t] && oj < mxj[t])) { mx[t] = omx; mxj[t] = oj; }
            float omn = __shfl_xor(mn[t], off, 64);
            int   on  = __shfl_xor(mnj[t], off, 64);
            if (omn < mn[t] || (omn == mn[t] && on < mnj[t])) { mn[t] = omn; mnj[t] = on; }
        }
        if (q == 0) {
            const int irow = i0 + w * 32 + t * 16 + m;
            part[(size_t)chunk * NROWS + irow] =
                make_float4(mx[t], __int_as_float(mxj[t]), mn[t], __int_as_float(mnj[t]));
        }
    }
}

// ---------------------------------------------------------------------------
// Kernel 3: chunk-merge + O(1) subset-position rank (prefix table) + loss.
// ---------------------------------------------------------------------------
__global__ __launch_bounds__(256) void rank_loss_kernel(const float* __restrict__ x,
                                                        const int* __restrict__ tgt,
                                                        const float4* __restrict__ part,
                                                        int S,
                                                        const int* __restrict__ cc,
                                                        const int* __restrict__ pre,
                                                        float* __restrict__ gacc) {
    __shared__ float s_acc[7];
    const int tid = threadIdx.x;
    if (tid < 7) s_acc[tid] = 0.0f;
    __syncthreads();

    const int wid = tid >> 6, lane = tid & 63;
    const int r = blockIdx.x * 4 + wid;
    const int ti = tgt[r];

    // merge chunk partials (chunk = lane; ascending chunk = ascending j)
    float bx = -FLT_MAX, bn = FLT_MAX;
    int bxj = 0x7fffffff, bnj = 0x7fffffff;
    if (lane < S) {
        float4 v = part[(size_t)lane * NROWS + r];
        bx = v.x; bxj = __float_as_int(v.y);
        bn = v.z; bnj = __float_as_int(v.w);
    }
    #pragma unroll
    for (int off = 1; off <= 8; off <<= 1) {
        float ox = __shfl_xor(bx, off, 64);
        int   oj = __shfl_xor(bxj, off, 64);
        if (ox > bx || (ox == bx && oj < bxj)) { bx = ox; bxj = oj; }
        float on = __shfl_xor(bn, off, 64);
        int   onj = __shfl_xor(bnj, off, 64);
        if (on < bn || (on == bn && onj < bnj)) { bn = on; bnj = onj; }
    }
    const int gp = __shfl(bxj, 0, 64);
    const int gn = __shfl(bnj, 0, 64);

    // subset positions via prefix table: O(1) per row
    // cp = #{j < gp : tgt[j]==ti};  cn = gn - #{j < gn : tgt[j]==ti}
    const int tjp = tgt[(gp & ~63) + lane];
    const int cp  = pre[(gp >> 6) * 64 + ti]
                  + __popcll(__ballot(tjp == ti && lane < (gp & 63)));
    const int tjn = tgt[(gn & ~63) + lane];
    const int sbn = pre[(gn >> 6) * 64 + ti]
                  + __popcll(__ballot(tjn == ti && lane < (gn & 63)));
    const int pp = cp, pn = gn - sbn;

    const float2 a  = *(const float2*)(x + (size_t)r  * DIM + lane * 2);
    const float2 p  = *(const float2*)(x + (size_t)pp * DIM + lane * 2);
    const float2 qv = *(const float2*)(x + (size_t)pn * DIM + lane * 2);
    float dap = (a.x - p.x) * (a.x - p.x) + (a.y - p.y) * (a.y - p.y);
    float dan = (a.x - qv.x) * (a.x - qv.x) + (a.y - qv.y) * (a.y - qv.y);
    float dpn = (p.x - qv.x) * (p.x - qv.x) + (p.y - qv.y) * (p.y - qv.y);
    float l1  = fabsf(a.x) + fabsf(a.y) + fabsf(p.x) + fabsf(p.y)
              + fabsf(qv.x) + fabsf(qv.y);
    #pragma unroll
    for (int off = 32; off > 0; off >>= 1) {
        dap += __shfl_xor(dap, off, 64);
        dan += __shfl_xor(dan, off, 64);
        dpn += __shfl_xor(dpn, off, 64);
        l1  += __shfl_xor(l1,  off, 64);
    }
    if (lane == 0) {
        int c = cc[ti];
        float vf = (c > 1 && (NROWS - c) >= 1) ? 1.0f : 0.0f;
        float tl = fmaxf(dap - dan + MARGIN, 0.0f) * vf;
        atomicAdd(&s_acc[0], tl);
        atomicAdd(&s_acc[1], (tl > 0.0f) ? 1.0f : 0.0f);
        atomicAdd(&s_acc[2], vf);
        atomicAdd(&s_acc[3], l1 * vf);
        atomicAdd(&s_acc[4], (dap - dan - dpn) * vf);
        atomicAdd(&s_acc[5], dap * vf);
        atomicAdd(&s_acc[6], dan * vf);
    }
    __syncthreads();
    if (tid < 7) atomicAdd(&gacc[tid], s_acc[tid]);
}

__global__ void final_kernel(const float* __restrict__ g, float* __restrict__ out) {
    if (threadIdx.x == 0) {
        float tl = g[0], nz = g[1], vc = g[2], l1 = g[3];
        float pw = g[4], apS = g[5], anS = g[6];
        out[0] = (nz == 0.0f) ? (tl / vc) : (tl / fmaxf(nz, 1.0f));
        out[1] = (l1 / vc) * (1.0f / 3.0f);
        out[2] = fmaxf(pw / vc, 0.0f);
        out[3] = vc;
        out[4] = apS / vc;
        out[5] = anS / vc;
    }
}

extern "C" void kernel_launch(void* const* d_in, const int* in_sizes, int n_in,
                              void* d_out, int out_size, void* d_ws, size_t ws_size,
                              hipStream_t stream) {
    const float* x   = (const float*)d_in[0];
    const int*   tgt = (const int*)d_in[1];
    float* out = (float*)d_out;
    char*  ws  = (char*)d_ws;

    const size_t fragBytes = (size_t)NROWS * DIM * 2 * 2;   // 4MB: H(2MB)+L(2MB)
    const size_t auxBytes  = (size_t)NROWS * 4 + 8 * 4 + 64 * 4 + NCHUNK * 64 * 4;

    int S = 16;
    bool fragpath = ws_size >= fragBytes + auxBytes + (size_t)4 * NROWS * 16;
    if (fragpath)
        while (ws_size < fragBytes + auxBytes + (size_t)S * NROWS * 16) S >>= 1;
    else {
        S = 16;
        while (S > 1 && ws_size < auxBytes + (size_t)S * NROWS * 16) S >>= 1;
    }
    const int chunk_len = NROWS / S;

    size_t off = fragpath ? fragBytes : 0;
    uint4*  fragH = (uint4*)ws;
    uint4*  fragL = (uint4*)(ws + fragBytes / 2);
    float*  xn   = (float*)(ws + off);            off += (size_t)NROWS * 4;
    float*  gacc = (float*)(ws + off);            off += 8 * 4;
    int*    cc   = (int*)(ws + off);              off += 64 * 4;
    int*    pre  = (int*)(ws + off);              off += (size_t)NCHUNK * 64 * 4;
    float4* part = (float4*)(ws + off);

    hipMemsetAsync(gacc, 0, (8 + 64) * sizeof(float), stream);
    xn_cc_kernel<<<NROWS / 4, 256, 0, stream>>>(x, tgt, xn, cc);
    prefix_kernel<<<1, 256, 0, stream>>>(tgt, pre);
    if (fragpath) {
        frag_kernel<<<NROWS / 16, 256, 0, stream>>>(x, fragH, fragL);
        mine_kernel<<<64 * S, 256, 0, stream>>>(fragH, fragL, tgt, xn, chunk_len, part);
    } else {
        mine_conv_kernel<<<64 * S, 256, 0, stream>>>(x, tgt, xn, chunk_len, part);
    }
    rank_loss_kernel<<<NROWS / 4, 256, 0, stream>>>(x, tgt, part, S, cc, pre, gacc);
    final_kernel<<<1, 64, 0, stream>>>(gacc, out);
}

// Round 5
// 129.578 us; speedup vs baseline: 7.7994x; 1.7065x over previous
//
#include <hip/hip_runtime.h>
#include <float.h>
#include <stdint.h>

#define NROWS 8192
#define DIM 128
#define MARGIN 0.5f
#define NCHUNK (NROWS / 64)   // 128 64-row chunks for the class-prefix table
#define RLBLOCKS (NROWS / 16) // 512 rank_loss blocks, 16 rows each

typedef __attribute__((ext_vector_type(8))) short short8;   // 8 bf16 = 4 VGPRs
typedef __attribute__((ext_vector_type(4))) float floatx4;  // MFMA C/D

// async global->LDS, 16B per lane; LDS dest = wave-uniform base + lane*16
__device__ __forceinline__ void load_lds16(const void* g, void* l) {
    __builtin_amdgcn_global_load_lds(
        (const __attribute__((address_space(1))) unsigned int*)g,
        (__attribute__((address_space(3))) unsigned int*)l, 16, 0, 0);
}

__device__ __forceinline__ void split_pack(const float* vv, unsigned* h, unsigned* l) {
    #pragma unroll
    for (int e = 0; e < 4; ++e) {
        unsigned u0 = __float_as_uint(vv[2 * e]);
        unsigned u1 = __float_as_uint(vv[2 * e + 1]);
        h[e] = (u0 >> 16) | (u1 & 0xffff0000u);
        float l0 = vv[2 * e]     - __uint_as_float(u0 & 0xffff0000u);
        float l1 = vv[2 * e + 1] - __uint_as_float(u1 & 0xffff0000u);
        l[e] = (__float_as_uint(l0) >> 16) | (__float_as_uint(l1) & 0xffff0000u);
    }
}

// ---------------------------------------------------------------------------
// Kernel 1: xn[i] = dot(x[i], x[i]).  (histogram moved to prefix_kernel —
// its same-line atomics were serializing)
// ---------------------------------------------------------------------------
__global__ __launch_bounds__(256) void xn_kernel(const float* __restrict__ x,
                                                 float* __restrict__ xn) {
    const int wid  = threadIdx.x >> 6;
    const int lane = threadIdx.x & 63;
    const int row  = blockIdx.x * 4 + wid;
    const float2 v = *(const float2*)(x + (size_t)row * DIM + lane * 2);
    float s = v.x * v.x + v.y * v.y;
    #pragma unroll
    for (int off = 32; off > 0; off >>= 1) s += __shfl_xor(s, off, 64);
    if (lane == 0) xn[row] = s;
}

// ---------------------------------------------------------------------------
// Kernel 1b: class-prefix table + class counts.
// pre[k*64+c] = #{ j < 64k : tgt[j]==c };  cc[c] = total count of class c.
// One block: LDS-atomic per-chunk histogram, then 64-lane scan over chunks.
// ---------------------------------------------------------------------------
__global__ __launch_bounds__(256) void prefix_kernel(const int* __restrict__ tgt,
                                                     int* __restrict__ pre,
                                                     int* __restrict__ cc) {
    __shared__ int cnt[NCHUNK][64];   // 32KB
    const int tid = threadIdx.x;
    for (int f = tid; f < NCHUNK * 64; f += 256) ((int*)cnt)[f] = 0;
    __syncthreads();
    for (int j = tid; j < NROWS; j += 256) atomicAdd(&cnt[j >> 6][tgt[j]], 1);
    __syncthreads();
    if (tid < 64) {
        int run = 0;
        for (int k = 0; k < NCHUNK; ++k) {
            pre[k * 64 + tid] = run;
            run += cnt[k][tid];
        }
        cc[tid] = run;
    }
}

// ---------------------------------------------------------------------------
// Kernel 1c: fragment-order bf16 hi/lo precompute (separate H and L arrays).
// Per 16-row tile b, k-chunk s: 64 lanes x 16B -> 1KB block at (b*4+s)*1KB.
// Fragment order: lane holds row lane&15, k = (lane>>4)*8 + e.
// ---------------------------------------------------------------------------
__global__ __launch_bounds__(256) void frag_kernel(const float* __restrict__ x,
                                                   uint4* __restrict__ fragH,
                                                   uint4* __restrict__ fragL) {
    const int t = threadIdx.x, b = blockIdx.x;
    const int s = t >> 6, lane = t & 63;
    const int row = b * 16 + (lane & 15);
    const int k0  = s * 32 + (lane >> 4) * 8;
    const float* xr = x + (size_t)row * DIM + k0;
    float4 va = *(const float4*)xr, vb = *(const float4*)(xr + 4);
    float vv[8] = {va.x, va.y, va.z, va.w, vb.x, vb.y, vb.z, vb.w};
    unsigned h[4], l[4];
    split_pack(vv, h, l);
    fragH[(size_t)(b * 4 + s) * 64 + lane] = make_uint4(h[0], h[1], h[2], h[3]);
    fragL[(size_t)(b * 4 + s) * 64 + lane] = make_uint4(l[0], l[1], l[2], l[3]);
}

// ---------------------------------------------------------------------------
// Kernel 2: MFMA mining, 2-pass split: G = (i_hi + i_lo) · j_hi.
// j-side stages HI limb only (16KB/tile DMA via global_load_lds x16B).
// Block = 4 waves, 128 i-rows; j split into S chunks across blocks.
// acc = mfma(jfrag, ifrag): C col=lane&15 = i, row = quad*4+reg = j.
// part layout: [row][chunk] (row-major, stride 16).
// ---------------------------------------------------------------------------
__global__ __launch_bounds__(256, 4) void mine_kernel(const uint4* __restrict__ fragH,
                                                      const uint4* __restrict__ fragL,
                                                      const int* __restrict__ tgt,
                                                      const float* __restrict__ xn,
                                                      int chunk_len,
                                                      float4* __restrict__ part) {
    __shared__ __align__(16) uint4 Sb[1024];   // 16KB: 16 (st,s) blocks x 1KB
    __shared__ float xnS[64];
    __shared__ int   tgtS[64];

    const int tid  = threadIdx.x;
    const int lane = tid & 63;
    const int w    = tid >> 6;
    const int m    = lane & 15;
    const int q    = lane >> 4;
    const int ib     = blockIdx.x & 63;
    const int chunk  = blockIdx.x >> 6;
    const int i0     = ib * 128;
    const int jbase0 = chunk * chunk_len;

    // i-fragments (hi + lo), coalesced 16B/lane, persist in regs
    short8 aih[2][4], ail[2][4];
    float xni[2]; int ti[2];
    #pragma unroll
    for (int t = 0; t < 2; ++t) {
        const int irow = i0 + w * 32 + t * 16 + m;
        xni[t] = xn[irow];
        ti[t]  = tgt[irow];
        const int itile = (i0 >> 4) + w * 2 + t;
        #pragma unroll
        for (int s = 0; s < 4; ++s) {
            aih[t][s] = *(const short8*)&fragH[(size_t)(itile * 4 + s) * 64 + lane];
            ail[t][s] = *(const short8*)&fragL[(size_t)(itile * 4 + s) * 64 + lane];
        }
    }

    float mx[2] = {-FLT_MAX, -FLT_MAX}, mn[2] = {FLT_MAX, FLT_MAX};
    int mxj[2] = {0, 0}, mnj[2] = {0, 0};

    const int ntiles = chunk_len >> 6;
    for (int jt = 0; jt < ntiles; ++jt) {
        const int j0 = jbase0 + jt * 64;
        __syncthreads();
        // stage 64 j-rows' HI fragments: linear 16KB DMA copy
        const char* g = (const char*)(fragH + (size_t)(j0 >> 4) * 256);
        #pragma unroll
        for (int it = 0; it < 4; ++it)
            load_lds16(g + it * 4096 + tid * 16,
                       (char*)Sb + it * 4096 + w * 1024);
        if (tid < 64) { xnS[tid] = xn[j0 + tid]; tgtS[tid] = tgt[j0 + tid]; }
        __syncthreads();   // drains vmcnt (global_load_lds) + lds writes

        #pragma unroll
        for (int st = 0; st < 4; ++st) {
            floatx4 acc0 = {0.f, 0.f, 0.f, 0.f};
            floatx4 acc1 = {0.f, 0.f, 0.f, 0.f};
            #pragma unroll
            for (int s = 0; s < 4; ++s) {
                short8 jh = *(const short8*)&Sb[(st * 4 + s) * 64 + lane];
                acc0 = __builtin_amdgcn_mfma_f32_16x16x32_bf16(jh, aih[0][s], acc0, 0, 0, 0);
                acc1 = __builtin_amdgcn_mfma_f32_16x16x32_bf16(jh, aih[1][s], acc1, 0, 0, 0);
                acc0 = __builtin_amdgcn_mfma_f32_16x16x32_bf16(jh, ail[0][s], acc0, 0, 0, 0);
                acc1 = __builtin_amdgcn_mfma_f32_16x16x32_bf16(jh, ail[1][s], acc1, 0, 0, 0);
            }
            float4 xnj4 = *(const float4*)&xnS[st * 16 + q * 4];
            int4   tj4  = *(const int4*)&tgtS[st * 16 + q * 4];
            const int jb = j0 + st * 16 + q * 4;
            float xnj[4] = {xnj4.x, xnj4.y, xnj4.z, xnj4.w};
            int   tj[4]  = {tj4.x, tj4.y, tj4.z, tj4.w};
            #pragma unroll
            for (int t = 0; t < 2; ++t) {
                floatx4 acc = t ? acc1 : acc0;
                #pragma unroll
                for (int r = 0; r < 4; ++r) {
                    // j ascends per lane -> strict compare keeps first occurrence
                    float d = fmaxf(fmaf(-2.0f, acc[r], xni[t] + xnj[r]), 0.0f);
                    if (tj[r] == ti[t]) { if (d > mx[t]) { mx[t] = d; mxj[t] = jb + r; } }
                    else                { if (d < mn[t]) { mn[t] = d; mnj[t] = jb + r; } }
                }
            }
        }
    }

    #pragma unroll
    for (int t = 0; t < 2; ++t) {
        #pragma unroll
        for (int off = 16; off <= 32; off <<= 1) {
            float omx = __shfl_xor(mx[t], off, 64);
            int   oj  = __shfl_xor(mxj[t], off, 64);
            if (omx > mx[t] || (omx == mx[t] && oj < mxj[t])) { mx[t] = omx; mxj[t] = oj; }
            float omn = __shfl_xor(mn[t], off, 64);
            int   on  = __shfl_xor(mnj[t], off, 64);
            if (omn < mn[t] || (omn == mn[t] && on < mnj[t])) { mn[t] = omn; mnj[t] = on; }
        }
        if (q == 0) {
            const int irow = i0 + w * 32 + t * 16 + m;
            part[(size_t)irow * 16 + chunk] =
                make_float4(mx[t], __int_as_float(mxj[t]), mn[t], __int_as_float(mnj[t]));
        }
    }
}

// ---------------------------------------------------------------------------
// Fallback mine (in-kernel conversion, 3-pass) for small ws_size.
// ---------------------------------------------------------------------------
__global__ __launch_bounds__(256) void mine_conv_kernel(const float* __restrict__ x,
                                                        const int* __restrict__ tgt,
                                                        const float* __restrict__ xn,
                                                        int chunk_len,
                                                        float4* __restrict__ part) {
    __shared__ __align__(16) short Bh[64][136];
    __shared__ __align__(16) short Bl[64][136];
    __shared__ float xnS[64];
    __shared__ int   tgtS[64];

    const int tid  = threadIdx.x;
    const int lane = tid & 63;
    const int w    = tid >> 6;
    const int m    = lane & 15;
    const int q    = lane >> 4;
    const int ib     = blockIdx.x & 63;
    const int chunk  = blockIdx.x >> 6;
    const int i0     = ib * 128;
    const int jbase0 = chunk * chunk_len;

    short8 aih[2][4], ail[2][4];
    float xni[2]; int ti[2];
    #pragma unroll
    for (int t = 0; t < 2; ++t) {
        const int irow = i0 + w * 32 + t * 16 + m;
        const float* xr = x + (size_t)irow * DIM;
        xni[t] = xn[irow]; ti[t] = tgt[irow];
        #pragma unroll
        for (int s = 0; s < 4; ++s) {
            const int k0 = s * 32 + q * 8;
            float4 va = *(const float4*)(xr + k0);
            float4 vb = *(const float4*)(xr + k0 + 4);
            float vv[8] = {va.x, va.y, va.z, va.w, vb.x, vb.y, vb.z, vb.w};
            unsigned h[4], l[4];
            split_pack(vv, h, l);
            aih[t][s] = *(short8*)h; ail[t][s] = *(short8*)l;
        }
    }

    float mx[2] = {-FLT_MAX, -FLT_MAX}, mn[2] = {FLT_MAX, FLT_MAX};
    int mxj[2] = {0, 0}, mnj[2] = {0, 0};

    const int ntiles = chunk_len >> 6;
    for (int jt = 0; jt < ntiles; ++jt) {
        const int j0 = jbase0 + jt * 64;
        __syncthreads();
        #pragma unroll
        for (int it = 0; it < 8; ++it) {
            const int f = tid + it * 256;
            const int row = f >> 5, kv = f & 31;
            float4 v = *(const float4*)(x + (size_t)(j0 + row) * DIM + kv * 4);
            float vv8[8] = {v.x, v.y, v.z, v.w, 0, 0, 0, 0};
            unsigned h[4], l[4];
            split_pack(vv8, h, l);
            *(uint2*)&Bh[row][kv * 4] = make_uint2(h[0], h[1]);
            *(uint2*)&Bl[row][kv * 4] = make_uint2(l[0], l[1]);
        }
        if (tid < 64) { xnS[tid] = xn[j0 + tid]; tgtS[tid] = tgt[j0 + tid]; }
        __syncthreads();

        #pragma unroll
        for (int st = 0; st < 4; ++st) {
            const int rb = st * 16;
            floatx4 acc0 = {0.f, 0.f, 0.f, 0.f};
            floatx4 acc1 = {0.f, 0.f, 0.f, 0.f};
            #pragma unroll
            for (int s = 0; s < 4; ++s) {
                short8 jh = *(const short8*)&Bh[rb + m][s * 32 + q * 8];
                short8 jl = *(const short8*)&Bl[rb + m][s * 32 + q * 8];
                acc0 = __builtin_amdgcn_mfma_f32_16x16x32_bf16(jh, aih[0][s], acc0, 0, 0, 0);
                acc1 = __builtin_amdgcn_mfma_f32_16x16x32_bf16(jh, aih[1][s], acc1, 0, 0, 0);
                acc0 = __builtin_amdgcn_mfma_f32_16x16x32_bf16(jl, aih[0][s], acc0, 0, 0, 0);
                acc1 = __builtin_amdgcn_mfma_f32_16x16x32_bf16(jl, aih[1][s], acc1, 0, 0, 0);
                acc0 = __builtin_amdgcn_mfma_f32_16x16x32_bf16(jh, ail[0][s], acc0, 0, 0, 0);
                acc1 = __builtin_amdgcn_mfma_f32_16x16x32_bf16(jh, ail[1][s], acc1, 0, 0, 0);
            }
            float4 xnj4 = *(const float4*)&xnS[rb + q * 4];
            int4   tj4  = *(const int4*)&tgtS[rb + q * 4];
            const int jb = j0 + rb + q * 4;
            float xnj[4] = {xnj4.x, xnj4.y, xnj4.z, xnj4.w};
            int   tj[4]  = {tj4.x, tj4.y, tj4.z, tj4.w};
            #pragma unroll
            for (int t = 0; t < 2; ++t) {
                floatx4 acc = t ? acc1 : acc0;
                #pragma unroll
                for (int r = 0; r < 4; ++r) {
                    float d = fmaxf(fmaf(-2.0f, acc[r], xni[t] + xnj[r]), 0.0f);
                    if (tj[r] == ti[t]) { if (d > mx[t]) { mx[t] = d; mxj[t] = jb + r; } }
                    else                { if (d < mn[t]) { mn[t] = d; mnj[t] = jb + r; } }
                }
            }
        }
    }

    #pragma unroll
    for (int t = 0; t < 2; ++t) {
        #pragma unroll
        for (int off = 16; off <= 32; off <<= 1) {
            float omx = __shfl_xor(mx[t], off, 64);
            int   oj  = __shfl_xor(mxj[t], off, 64);
            if (omx > mx[t] || (omx == mx[t] && oj < mxj[t])) { mx[t] = omx; mxj[t] = oj; }
            float omn = __shfl_xor(mn[t], off, 64);
            int   on  = __shfl_xor(mnj[t], off, 64);
            if (omn < mn[t] || (omn == mn[t] && on < mnj[t])) { mn[t] = omn; mnj[t] = on; }
        }
        if (q == 0) {
            const int irow = i0 + w * 32 + t * 16 + m;
            part[(size_t)irow * 16 + chunk] =
                make_float4(mx[t], __int_as_float(mxj[t]), mn[t], __int_as_float(mnj[t]));
        }
    }
}

// ---------------------------------------------------------------------------
// Kernel 3: chunk-merge + O(1) rank + loss terms. 512 blocks x 16 rows.
// Register accumulation per wave -> LDS combine -> NON-ATOMIC blockpart store
// (2048-block same-line atomicAdd tail was the 65us serializer in R4).
// ---------------------------------------------------------------------------
__global__ __launch_bounds__(256) void rank_loss_kernel(const float* __restrict__ x,
                                                        const int* __restrict__ tgt,
                                                        const float4* __restrict__ part,
                                                        int S,
                                                        const int* __restrict__ cc,
                                                        const int* __restrict__ pre,
                                                        float* __restrict__ blockpart) {
    __shared__ float s_red[4][8];
    const int tid = threadIdx.x, w = tid >> 6, lane = tid & 63;
    const int r0 = blockIdx.x * 16 + w * 4;

    float a0 = 0, a1 = 0, a2 = 0, a3 = 0, a4 = 0, a5 = 0, a6 = 0;

    #pragma unroll
    for (int rr = 0; rr < 4; ++rr) {
        const int r  = r0 + rr;
        const int ti = tgt[r];

        // merge chunk partials (chunk = lane; ascending chunk = ascending j)
        float bx = -FLT_MAX, bn = FLT_MAX;
        int bxj = 0x7fffffff, bnj = 0x7fffffff;
        if (lane < S) {
            float4 v = part[(size_t)r * 16 + lane];
            bx = v.x; bxj = __float_as_int(v.y);
            bn = v.z; bnj = __float_as_int(v.w);
        }
        #pragma unroll
        for (int off = 1; off <= 8; off <<= 1) {
            float ox = __shfl_xor(bx, off, 64);
            int   oj = __shfl_xor(bxj, off, 64);
            if (ox > bx || (ox == bx && oj < bxj)) { bx = ox; bxj = oj; }
            float on = __shfl_xor(bn, off, 64);
            int  onj = __shfl_xor(bnj, off, 64);
            if (on < bn || (on == bn && onj < bnj)) { bn = on; bnj = onj; }
        }
        const int gp = __shfl(bxj, 0, 64);
        const int gn = __shfl(bnj, 0, 64);

        // subset positions via prefix table: O(1) per row
        const int tjp = tgt[(gp & ~63) + lane];
        const int cp  = pre[(gp >> 6) * 64 + ti]
                      + __popcll(__ballot(tjp == ti && lane < (gp & 63)));
        const int tjn = tgt[(gn & ~63) + lane];
        const int sbn = pre[(gn >> 6) * 64 + ti]
                      + __popcll(__ballot(tjn == ti && lane < (gn & 63)));
        const int pp = cp, pn = gn - sbn;

        const float2 a  = *(const float2*)(x + (size_t)r  * DIM + lane * 2);
        const float2 p  = *(const float2*)(x + (size_t)pp * DIM + lane * 2);
        const float2 qv = *(const float2*)(x + (size_t)pn * DIM + lane * 2);
        float dap = (a.x - p.x) * (a.x - p.x) + (a.y - p.y) * (a.y - p.y);
        float dan = (a.x - qv.x) * (a.x - qv.x) + (a.y - qv.y) * (a.y - qv.y);
        float dpn = (p.x - qv.x) * (p.x - qv.x) + (p.y - qv.y) * (p.y - qv.y);
        float l1  = fabsf(a.x) + fabsf(a.y) + fabsf(p.x) + fabsf(p.y)
                  + fabsf(qv.x) + fabsf(qv.y);
        #pragma unroll
        for (int off = 32; off > 0; off >>= 1) {
            dap += __shfl_xor(dap, off, 64);
            dan += __shfl_xor(dan, off, 64);
            dpn += __shfl_xor(dpn, off, 64);
            l1  += __shfl_xor(l1,  off, 64);
        }
        // all lanes hold totals; accumulate on lane 0 only
        if (lane == 0) {
            int c = cc[ti];
            float vf = (c > 1 && (NROWS - c) >= 1) ? 1.0f : 0.0f;
            float tl = fmaxf(dap - dan + MARGIN, 0.0f) * vf;
            a0 += tl;
            a1 += (tl > 0.0f) ? 1.0f : 0.0f;
            a2 += vf;
            a3 += l1 * vf;
            a4 += (dap - dan - dpn) * vf;
            a5 += dap * vf;
            a6 += dan * vf;
        }
    }

    if (lane == 0) {
        s_red[w][0] = a0; s_red[w][1] = a1; s_red[w][2] = a2; s_red[w][3] = a3;
        s_red[w][4] = a4; s_red[w][5] = a5; s_red[w][6] = a6; s_red[w][7] = 0.f;
    }
    __syncthreads();
    if (tid < 8)
        blockpart[blockIdx.x * 8 + tid] =
            s_red[0][tid] + s_red[1][tid] + s_red[2][tid] + s_red[3][tid];
}

// ---------------------------------------------------------------------------
// Kernel 4: reduce blockpart deterministically, finalize 6 outputs.
// ---------------------------------------------------------------------------
__global__ __launch_bounds__(256) void final_kernel(const float* __restrict__ bp,
                                                    float* __restrict__ out) {
    __shared__ float red[32][8];
    const int tid = threadIdx.x, k = tid & 7;
    float s = 0.0f;
    for (int i = tid >> 3; i < RLBLOCKS; i += 32) s += bp[i * 8 + k];
    red[tid >> 3][k] = s;
    __syncthreads();
    if (tid == 0) {
        float tot[7];
        #pragma unroll
        for (int kk = 0; kk < 7; ++kk) {
            float t = 0.0f;
            for (int i = 0; i < 32; ++i) t += red[i][kk];
            tot[kk] = t;
        }
        float tl = tot[0], nz = tot[1], vc = tot[2], l1 = tot[3];
        float pw = tot[4], apS = tot[5], anS = tot[6];
        out[0] = (nz == 0.0f) ? (tl / vc) : (tl / fmaxf(nz, 1.0f));
        out[1] = (l1 / vc) * (1.0f / 3.0f);
        out[2] = fmaxf(pw / vc, 0.0f);
        out[3] = vc;
        out[4] = apS / vc;
        out[5] = anS / vc;
    }
}

extern "C" void kernel_launch(void* const* d_in, const int* in_sizes, int n_in,
                              void* d_out, int out_size, void* d_ws, size_t ws_size,
                              hipStream_t stream) {
    const float* x   = (const float*)d_in[0];
    const int*   tgt = (const int*)d_in[1];
    float* out = (float*)d_out;
    char*  ws  = (char*)d_ws;

    const size_t fragBytes = (size_t)NROWS * DIM * 2 * 2;   // 4MB: H(2MB)+L(2MB)
    const size_t partBytes = (size_t)NROWS * 16 * 16;       // 2MB, stride 16 always
    const size_t auxBytes  = (size_t)NROWS * 4 + NCHUNK * 64 * 4 + 64 * 4
                           + RLBLOCKS * 8 * 4;

    bool fragpath = ws_size >= fragBytes + auxBytes + partBytes;
    int S = 16;
    if (!fragpath) { /* still need part+aux */ }

    size_t off = fragpath ? fragBytes : 0;
    uint4*  fragH = (uint4*)ws;
    uint4*  fragL = (uint4*)(ws + fragBytes / 2);
    float*  xn   = (float*)(ws + off);            off += (size_t)NROWS * 4;
    int*    pre  = (int*)(ws + off);              off += (size_t)NCHUNK * 64 * 4;
    int*    cc   = (int*)(ws + off);              off += 64 * 4;
    float*  bp   = (float*)(ws + off);            off += (size_t)RLBLOCKS * 8 * 4;
    float4* part = (float4*)(ws + off);

    const int chunk_len = NROWS / S;

    xn_kernel<<<NROWS / 4, 256, 0, stream>>>(x, xn);
    prefix_kernel<<<1, 256, 0, stream>>>(tgt, pre, cc);
    if (fragpath) {
        frag_kernel<<<NROWS / 16, 256, 0, stream>>>(x, fragH, fragL);
        mine_kernel<<<64 * S, 256, 0, stream>>>(fragH, fragL, tgt, xn, chunk_len, part);
    } else {
        mine_conv_kernel<<<64 * S, 256, 0, stream>>>(x, tgt, xn, chunk_len, part);
    }
    rank_loss_kernel<<<RLBLOCKS, 256, 0, stream>>>(x, tgt, part, S, cc, pre, bp);
    final_kernel<<<1, 256, 0, stream>>>(bp, out);
}